// Round 5
// baseline (3375.352 us; speedup 1.0000x reference)
//
#include <hip/hip_runtime.h>
#include <hip/hip_bf16.h>

typedef __attribute__((ext_vector_type(8))) short short8;
typedef __attribute__((ext_vector_type(4))) float f32x4;
typedef unsigned int u32;
typedef unsigned short u16;

#define T_STEPS 512
#define B_SZ    128
#define I_SZ    512
#define U_SZ    1024
#define K_TOT   1536   // 512 x-part + 1024 h-part

// ws layout (bytes)
#define XB_OFF   0            // X as bf16 [B][T][I] = 67,108,864 B
#define WC_OFF   67108864     // W packed [gcol][k] bf16 = 12,582,912 B
#define FLAG_OFF 79691776     // 256 u32 flags (8 clusters x 32)
#define HBUF_OFF 79708160     // [cl 8][2][16][1024] bf16 = 524,288 B
// total 80,232,448 B

__device__ __forceinline__ u16 f2bf(float f) {
  u32 u = __float_as_uint(f);
  u32 r = (u + 0x7fffu + ((u >> 16) & 1u)) >> 16;   // RNE; inputs finite
  return (u16)r;
}
__device__ __forceinline__ float sigm(float x) { return 1.f / (1.f + __expf(-x)); }
__device__ __forceinline__ float tanh_s(float x) {
  float ax = fabsf(x);
  float e  = __expf(-2.f * ax);
  float t  = (1.f - e) / (1.f + e);
  return copysignf(t, x);
}

// ---- prep kernels ---------------------------------------------------------
__global__ void k_convX(const float* __restrict__ X, u16* __restrict__ Xb) {
  u32 i = blockIdx.x * 256u + threadIdx.x;            // covers 8,388,608 exactly
  float4 v = reinterpret_cast<const float4*>(X)[i];
  uint2 o;
  o.x = (u32)f2bf(v.x) | ((u32)f2bf(v.y) << 16);
  o.y = (u32)f2bf(v.z) | ((u32)f2bf(v.w) << 16);
  reinterpret_cast<uint2*>(Xb)[i] = o;
}

__global__ void k_packW(const float* __restrict__ Wih, const float* __restrict__ Whh,
                        u16* __restrict__ Wc) {
  const int gcol = blockIdx.x;
  for (int k = threadIdx.x; k < K_TOT; k += 256) {
    float v = (k < I_SZ) ? Wih[(size_t)gcol * I_SZ + k]
                         : Whh[(size_t)gcol * U_SZ + (k - I_SZ)];
    Wc[(size_t)gcol * K_TOT + k] = f2bf(v);
  }
}

__global__ void k_zero(u32* __restrict__ hz, u32* __restrict__ flags) {
  u32 i = blockIdx.x * 256u + threadIdx.x;            // 513 blocks
  if (i < 131072u)      hz[i] = 0u;                   // both h buffers (524,288 B)
  else if (i < 131328u) flags[i - 131072u] = 0u;      // 256 flags
}

// ---- PROVEN (R3) communication primitives ---------------------------------
// h data: sc0 sc1 (bypass L1+L2 -> L3/IF coherence point)
__device__ __forceinline__ short8 ld_h16(const u16* p) {
  short8 r;
  asm volatile("global_load_dwordx4 %0, %1, off sc0 sc1" : "=v"(r) : "v"(p));
  return r;   // NOT ready until s_waitcnt vmcnt(0)
}
__device__ __forceinline__ void st_h(u16* p, u32 v) {
  asm volatile("global_store_short %0, %1, off sc0 sc1" :: "v"(p), "v"(v) : "memory");
}

// ---- persistent scan ------------------------------------------------------
// 256 WGs x 512 thr, 1 WG/CU. cluster cl = wg>>5 (8 clusters x 16 batch rows,
// fully independent LSTMs). wloc = wg&31 -> u0 = wloc*32 (128 gate-cols =
// 4 gates x 32 units). Waves: cw = wid>>1 (gate), kq = wid&1 (K half, 768).
// K chunks of 32: chunk = iter*2 + kq, iter 0..23; chunks 0..15 = x, 16..47 = h.
// Per wave: 24 iters x 2 col-frags = 48 MFMA. W fully in VGPRs (192/lane).
__global__ __launch_bounds__(512, 2)
void lstm_scan(const u16* __restrict__ Xb, const u16* __restrict__ Wc,
               const float* __restrict__ bih, const float* __restrict__ bhh,
               u16* __restrict__ hbuf, u32* __restrict__ flags,
               float* __restrict__ out) {
  __shared__ __align__(16) char hst[32768];           // h panel [16][1024] bf16, swz
  __shared__ __align__(16) float gbuf[2][128][20];    // [kq][col][row16+pad]

  const int tid  = threadIdx.x;
  const int wg   = blockIdx.x;
  const int cl   = wg >> 5;                           // cluster (fixed, placement-free)
  const int wloc = wg & 31;
  const int u0   = wloc * 32;
  const int wid  = tid >> 6;
  const int lane = tid & 63;
  const int l15  = lane & 15;
  const int kg   = lane >> 4;
  const int cw   = wid >> 1;                          // gate 0..3
  const int kq   = wid & 1;                           // K half
  const int swzr = (l15 & 7) << 4;

  // --- persistent W fragments: all in VGPRs (192 regs) ---
  short8 Bf_x[8][2], Bf_h[16][2];
  #pragma unroll
  for (int cf = 0; cf < 2; ++cf) {
    const int lc   = cw * 32 + cf * 16 + l15;         // local col = gate*32+unit
    const int gcol = (lc >> 5) * 1024 + u0 + (lc & 31);
    const u16* wrow = Wc + (size_t)gcol * K_TOT;
    #pragma unroll
    for (int i = 0; i < 8; ++i) {
      const int k = (i * 2 + kq) * 32 + kg * 8;       // 0..511
      Bf_x[i][cf] = *reinterpret_cast<const short8*>(wrow + k);
    }
    #pragma unroll
    for (int ih = 0; ih < 16; ++ih) {
      const int k = ((8 + ih) * 2 + kq) * 32 + kg * 8; // 512..1535
      Bf_h[ih][cf] = *reinterpret_cast<const short8*>(wrow + k);
    }
  }

  // --- cell ownership: thread -> (row, unit) ---
  const int row  = tid >> 5;                          // 0..15
  const int uloc = tid & 31;                          // 0..31
  const int ug   = u0 + uloc;
  float bsum[4];
  #pragma unroll
  for (int g = 0; g < 4; ++g) bsum[g] = bih[g * 1024 + ug] + bhh[g * 1024 + ug];
  float c_state = 0.f;
  const int rowg = cl * 16 + row;
  float* orow = out + (size_t)rowg * (T_STEPS * U_SZ) + ug;
  u16* hb_cl  = hbuf + cl * 32768;                    // [2][16][1024]
  u32* myflag = flags + (cl << 5) + wloc;
  u32* pollp  = flags + (cl << 5) + (lane & 31);

  // --- x A-operand row pointer (cluster rows cl*16 + l15) ---
  const u16* xrow = Xb + ((size_t)(cl * 16 + l15)) * (T_STEPS * I_SZ);

  for (int t = 0; t < T_STEPS; ++t) {
    const u16* hsrc = hb_cl + ((t & 1) ^ 1) * 16384;
    u16*       hdst = hb_cl + (t & 1) * 16384;
    const u16* px   = xrow + (size_t)t * I_SZ;

    f32x4 acc[2];
    acc[0] = (f32x4){0.f, 0.f, 0.f, 0.f};
    acc[1] = (f32x4){0.f, 0.f, 0.f, 0.f};

    // ---- x-phase: no h dependence; hides flag/poll latency ----
    #pragma unroll
    for (int i = 0; i < 8; ++i) {
      const int k = (i * 2 + kq) * 32 + kg * 8;       // < 512
      const short8 a = *reinterpret_cast<const short8*>(px + k);
      #pragma unroll
      for (int cf = 0; cf < 2; ++cf)
        acc[cf] = __builtin_amdgcn_mfma_f32_16x16x32_bf16(a, Bf_x[i][cf], acc[cf], 0, 0, 0);
    }

    // ---- wait for h_{t-1}: 32 flags of MY cluster >= t (proven atomics) ----
    if (tid < 64) {
      for (;;) {
        const u32 v = __hip_atomic_load(pollp, __ATOMIC_RELAXED, __HIP_MEMORY_SCOPE_AGENT);
        const bool ok = (lane < 32) ? (v >= (u32)t) : true;
        if (__all((int)ok)) break;
        __builtin_amdgcn_s_sleep(1);
      }
    }
    __syncthreads();

    // ---- stage h panel (32 KB) into LDS, swizzled; sc0sc1 loads ----
    short8 hv[4];
    #pragma unroll
    for (int j = 0; j < 4; ++j) {
      const int c  = j * 512 + tid;                   // 2048 chunks of 16B
      const int hr = c & 15;
      const int k8 = c >> 4;                          // 0..127
      hv[j] = ld_h16(hsrc + hr * 1024 + k8 * 8);
    }
    asm volatile("s_waitcnt vmcnt(0)" ::: "memory");
    #pragma unroll
    for (int j = 0; j < 4; ++j) {
      const int c  = j * 512 + tid;
      const int hr = c & 15;
      const int k8 = c >> 4;
      *reinterpret_cast<short8*>(hst + ((hr * 2048 + k8 * 16) ^ ((hr & 7) << 4))) = hv[j];
    }
    __syncthreads();                                  // (A) hst ready

    // ---- h-phase: A from LDS, W from regs ----
    #pragma unroll
    for (int ih = 0; ih < 16; ++ih) {
      const int kb = ((8 + ih) * 2 + kq) * 64 + kg * 16 - 1024;  // byte in row
      const short8 a = *reinterpret_cast<const short8*>(hst + ((l15 * 2048 + kb) ^ swzr));
      #pragma unroll
      for (int cf = 0; cf < 2; ++cf)
        acc[cf] = __builtin_amdgcn_mfma_f32_16x16x32_bf16(a, Bf_h[ih][cf], acc[cf], 0, 0, 0);
    }

    // ---- exchange partials. C/D: col=lane&15, row=(lane>>4)*4+j ----
    #pragma unroll
    for (int cf = 0; cf < 2; ++cf) {
      const int lc = cw * 32 + cf * 16 + l15;
      *reinterpret_cast<float4*>(&gbuf[kq][lc][kg * 4]) =
          *reinterpret_cast<float4*>(&acc[cf]);
    }
    __syncthreads();                                  // (B)

    // ---- cell update: one (row, unit) per thread ----
    float gs[4];
    #pragma unroll
    for (int g = 0; g < 4; ++g) {
      const int col = g * 32 + uloc;
      gs[g] = bsum[g] + gbuf[0][col][row] + gbuf[1][col][row];
    }
    const float ig = sigm(gs[0]);
    const float fg = sigm(gs[1]);
    const float gg = tanh_s(gs[2]);
    const float og = sigm(gs[3]);
    c_state = fg * c_state + ig * gg;
    const float h = og * tanh_s(c_state);

    orow[(size_t)t * U_SZ] = h;                       // fp32 out (plain)
    st_h(hdst + row * 1024 + ug, (u32)f2bf(h));       // bf16 h -> L3

    // ---- publish: per-thread drain, barrier, one agent flag (R3-proven) ----
    asm volatile("s_waitcnt vmcnt(0)" ::: "memory");
    __syncthreads();                                  // (C) also WAR-protects hst/gbuf
    if (tid == 0)
      __hip_atomic_store(myflag, (u32)(t + 1), __ATOMIC_RELAXED, __HIP_MEMORY_SCOPE_AGENT);
  }
}

// ---- launch ---------------------------------------------------------------
extern "C" void kernel_launch(void* const* d_in, const int* in_sizes, int n_in,
                              void* d_out, int out_size, void* d_ws, size_t ws_size,
                              hipStream_t stream) {
  const float* X   = (const float*)d_in[0];
  const float* Wih = (const float*)d_in[1];
  const float* Whh = (const float*)d_in[2];
  const float* bih = (const float*)d_in[3];
  const float* bhh = (const float*)d_in[4];
  float* out = (float*)d_out;
  char*  ws  = (char*)d_ws;

  u16* Xb    = (u16*)(ws + XB_OFF);
  u16* Wc    = (u16*)(ws + WC_OFF);
  u32* flags = (u32*)(ws + FLAG_OFF);
  u16* hbuf  = (u16*)(ws + HBUF_OFF);

  hipLaunchKernelGGL(k_convX, dim3(32768), dim3(256), 0, stream, X, Xb);
  hipLaunchKernelGGL(k_packW, dim3(4096), dim3(256), 0, stream, Wih, Whh, Wc);
  hipLaunchKernelGGL(k_zero,  dim3(513),  dim3(256), 0, stream, (u32*)hbuf, flags);

  void* args[] = {(void*)&Xb, (void*)&Wc, (void*)&bih, (void*)&bhh,
                  (void*)&hbuf, (void*)&flags, (void*)&out};
  hipLaunchCooperativeKernel((void*)lstm_scan, dim3(256), dim3(512), args, 0, stream);
}

// Round 6
// 2584.076 us; speedup vs baseline: 1.3062x; 1.3062x over previous
//
#include <hip/hip_runtime.h>
#include <hip/hip_bf16.h>

typedef __attribute__((ext_vector_type(8))) short short8;
typedef __attribute__((ext_vector_type(4))) float f32x4;
typedef unsigned int u32;
typedef unsigned short u16;

#define T_STEPS 512
#define B_SZ    128
#define I_SZ    512
#define U_SZ    1024
#define K_TOT   1536   // 512 x-part + 1024 h-part

// ws layout (bytes)
#define XB_OFF   0            // X as bf16 [B][T][I] = 67,108,864 B
#define WC_OFF   67108864     // W packed [gcol][k] bf16 = 12,582,912 B
#define FLAG_OFF 79691776     // 256 u32 flags (4 clusters x 64)
#define HBUF_OFF 79708160     // [2][128][1024] bf16 = 524,288 B
// total 80,232,448 B

__device__ __forceinline__ u16 f2bf(float f) {
  u32 u = __float_as_uint(f);
  u32 r = (u + 0x7fffu + ((u >> 16) & 1u)) >> 16;   // RNE; inputs finite
  return (u16)r;
}
__device__ __forceinline__ float sigm(float x) { return 1.f / (1.f + __expf(-x)); }
__device__ __forceinline__ float tanh_s(float x) {
  float ax = fabsf(x);
  float e  = __expf(-2.f * ax);
  float t  = (1.f - e) / (1.f + e);
  return copysignf(t, x);
}

// ---- prep kernels ---------------------------------------------------------
__global__ void k_convX(const float* __restrict__ X, u16* __restrict__ Xb) {
  u32 i = blockIdx.x * 256u + threadIdx.x;            // covers 8,388,608 exactly
  float4 v = reinterpret_cast<const float4*>(X)[i];
  uint2 o;
  o.x = (u32)f2bf(v.x) | ((u32)f2bf(v.y) << 16);
  o.y = (u32)f2bf(v.z) | ((u32)f2bf(v.w) << 16);
  reinterpret_cast<uint2*>(Xb)[i] = o;
}

__global__ void k_packW(const float* __restrict__ Wih, const float* __restrict__ Whh,
                        u16* __restrict__ Wc) {
  const int gcol = blockIdx.x;
  for (int k = threadIdx.x; k < K_TOT; k += 256) {
    float v = (k < I_SZ) ? Wih[(size_t)gcol * I_SZ + k]
                         : Whh[(size_t)gcol * U_SZ + (k - I_SZ)];
    Wc[(size_t)gcol * K_TOT + k] = f2bf(v);
  }
}

__global__ void k_zero(u32* __restrict__ hz, u32* __restrict__ flags) {
  u32 i = blockIdx.x * 256u + threadIdx.x;            // 513 blocks
  if (i < 131072u)      hz[i] = 0u;                   // both h buffers
  else if (i < 131328u) flags[i - 131072u] = 0u;      // 256 flags
}

// ---- communication primitives (R2/R3-proven) ------------------------------
// h data: sc0 sc1 (bypass L1+L2 -> coherent at L3)
__device__ __forceinline__ short8 ld_h16(const u16* p) {
  short8 r;
  asm volatile("global_load_dwordx4 %0, %1, off sc0 sc1" : "=v"(r) : "v"(p));
  return r;   // NOT ready until s_waitcnt vmcnt(0)
}
__device__ __forceinline__ void st_h(u16* p, u32 v) {
  asm volatile("global_store_short %0, %1, off sc0 sc1" :: "v"(p), "v"(v) : "memory");
}
// W load: asm volatile so the register allocator CANNOT rematerialize/sink it
// into the t-loop -> the 24 fragments stay resident in VGPRs for all 512 steps.
__device__ __forceinline__ short8 ld_w16(const u16* p) {
  short8 r;
  asm volatile("global_load_dwordx4 %0, %1, off" : "=v"(r) : "v"(p));
  return r;   // NOT ready until s_waitcnt vmcnt(0)
}

// ---- persistent scan ------------------------------------------------------
// 256 WGs x 512 thr, 1 WG/CU. cluster cl = wg>>6 (4 clusters x 32 batch rows,
// independent LSTMs). wloc = wg&63 -> u0 = wloc*16 (64 gate-cols = 4g x 16u).
// Waves: kw = wid (8-way K split, 192 K each; zero A/W duplication in WG).
// Per wave: 2 row-tiles x 4 col-frags x 6 k-iters = 48 MFMA; W = 24 frags
// (96 VGPR) FORCED resident. K map: chunk = i*8+kw; i<2 -> x, i>=2 -> h.
__global__ __launch_bounds__(512, 2)
void lstm_scan(const u16* __restrict__ Xb, const u16* __restrict__ Wc,
               const float* __restrict__ bih, const float* __restrict__ bhh,
               u16* __restrict__ hbuf, u32* __restrict__ flags,
               float* __restrict__ out) {
  __shared__ __align__(16) float gbuf[8][64][36];     // [kw][col][row32+pad] 73,728 B

  const int tid  = threadIdx.x;
  const int wg   = blockIdx.x;
  const int cl   = wg >> 6;                           // cluster
  const int wloc = wg & 63;
  const int rb   = cl * 32;                           // batch row base
  const int u0   = wloc * 16;                         // unit base
  const int wid  = tid >> 6;
  const int lane = tid & 63;
  const int l15  = lane & 15;
  const int kg   = lane >> 4;
  const int kw   = wid;                               // 8-way K split

  // --- persistent W fragments, FORCED into VGPRs (asm volatile loads) ---
  short8 Bf[6][4];                                    // 96 VGPRs
  #pragma unroll
  for (int ct = 0; ct < 4; ++ct) {
    const int gcol = ct * 1024 + u0 + l15;            // gate=ct, unit=u0+l15
    const u16* wrow = Wc + (size_t)gcol * K_TOT;
    #pragma unroll
    for (int i = 0; i < 6; ++i) {
      const int k = (i * 8 + kw) * 32 + kg * 8;
      Bf[i][ct] = ld_w16(wrow + k);
    }
  }
  asm volatile("s_waitcnt vmcnt(0)" ::: "memory");
  __builtin_amdgcn_sched_barrier(0);

  // --- cell ownership: thread -> (row rb+b_l, unit u0+uu) ---
  const int b_l = tid >> 4;                           // 0..31
  const int uu  = tid & 15;                           // 0..15
  const int ug  = u0 + uu;
  float bsum[4];
  #pragma unroll
  for (int g = 0; g < 4; ++g) bsum[g] = bih[g * 1024 + ug] + bhh[g * 1024 + ug];
  float c_state = 0.f;
  float* orow = out + (size_t)(rb + b_l) * (T_STEPS * U_SZ) + ug;
  const int hidx = (rb + b_l) * U_SZ + ug;
  u32* myflag = flags + (cl << 6) + wloc;
  u32* pollp  = flags + (cl << 6) + lane;             // 64 cluster flags

  // --- A-operand rows (per wave: 2 row-tiles) ---
  const int r0 = rb + l15;
  const int r1 = r0 + 16;
  const u16* xrow0 = Xb + (size_t)r0 * (T_STEPS * I_SZ);
  const u16* xrow1 = Xb + (size_t)r1 * (T_STEPS * I_SZ);

  for (int t = 0; t < T_STEPS; ++t) {
    const u16* hsrc = hbuf + ((t & 1) ^ 1) * (B_SZ * U_SZ);
    u16*       hdst = hbuf + (t & 1) * (B_SZ * U_SZ);
    const u16* px0 = xrow0 + (size_t)t * I_SZ;
    const u16* px1 = xrow1 + (size_t)t * I_SZ;

    f32x4 acc[2][4];
    #pragma unroll
    for (int rt = 0; rt < 2; ++rt)
      #pragma unroll
      for (int ct = 0; ct < 4; ++ct)
        acc[rt][ct] = (f32x4){0.f, 0.f, 0.f, 0.f};

    // ---- x-phase: no h dependence; hides producers' publish latency ----
    #pragma unroll
    for (int i = 0; i < 2; ++i) {
      const int k = (i * 8 + kw) * 32 + kg * 8;       // < 512
      const short8 a0 = *reinterpret_cast<const short8*>(px0 + k);
      const short8 a1 = *reinterpret_cast<const short8*>(px1 + k);
      #pragma unroll
      for (int ct = 0; ct < 4; ++ct) {
        acc[0][ct] = __builtin_amdgcn_mfma_f32_16x16x32_bf16(a0, Bf[i][ct], acc[0][ct], 0, 0, 0);
        acc[1][ct] = __builtin_amdgcn_mfma_f32_16x16x32_bf16(a1, Bf[i][ct], acc[1][ct], 0, 0, 0);
      }
    }

    // ---- wait for h_{t-1}: every wave polls the 64 cluster flags itself
    //      (no barrier on this path; t=0 passes immediately) ----
    for (;;) {
      const u32 v = __hip_atomic_load(pollp, __ATOMIC_RELAXED, __HIP_MEMORY_SCOPE_AGENT);
      if (__all((int)(v >= (u32)t))) break;
      __builtin_amdgcn_s_sleep(1);
    }

    // ---- h-phase: batch all 8 L3 loads, one drain, then MFMA ----
    short8 hA[4][2];
    #pragma unroll
    for (int ih = 0; ih < 4; ++ih) {
      const int ku = ((2 + ih) * 8 + kw) * 32 + kg * 8 - 512;   // 0..1023
      hA[ih][0] = ld_h16(hsrc + (size_t)r0 * U_SZ + ku);
      hA[ih][1] = ld_h16(hsrc + (size_t)r1 * U_SZ + ku);
    }
    asm volatile("s_waitcnt vmcnt(0)" ::: "memory");
    __builtin_amdgcn_sched_barrier(0);
    #pragma unroll
    for (int ih = 0; ih < 4; ++ih)
      #pragma unroll
      for (int ct = 0; ct < 4; ++ct) {
        acc[0][ct] = __builtin_amdgcn_mfma_f32_16x16x32_bf16(hA[ih][0], Bf[2 + ih][ct], acc[0][ct], 0, 0, 0);
        acc[1][ct] = __builtin_amdgcn_mfma_f32_16x16x32_bf16(hA[ih][1], Bf[2 + ih][ct], acc[1][ct], 0, 0, 0);
      }

    // ---- partials -> LDS (b128). C/D: col=lane&15, row=(lane>>4)*4+j ----
    #pragma unroll
    for (int rt = 0; rt < 2; ++rt)
      #pragma unroll
      for (int ct = 0; ct < 4; ++ct)
        *reinterpret_cast<float4*>(&gbuf[kw][ct * 16 + l15][rt * 16 + kg * 4]) =
            *reinterpret_cast<float4*>(&acc[rt][ct]);
    __syncthreads();                                  // (B) gbuf ready

    // ---- cell update: one (row, unit) per thread ----
    float gs[4];
    #pragma unroll
    for (int g = 0; g < 4; ++g) {
      float s = bsum[g];
      #pragma unroll
      for (int k2 = 0; k2 < 8; ++k2) s += gbuf[k2][g * 16 + uu][b_l];
      gs[g] = s;
    }
    const float ig = sigm(gs[0]);
    const float fg = sigm(gs[1]);
    const float gg = tanh_s(gs[2]);
    const float og = sigm(gs[3]);
    c_state = fg * c_state + ig * gg;
    const float h = og * tanh_s(c_state);

    // ---- publish FIRST (h store + drain + barrier + flag), out store after ----
    st_h(hdst + hidx, (u32)f2bf(h));                  // bf16 h -> L3
    asm volatile("s_waitcnt vmcnt(0)" ::: "memory");
    __syncthreads();                                  // (C) all h stores drained; WAR-protects gbuf
    if (tid == 0)
      __hip_atomic_store(myflag, (u32)(t + 1), __ATOMIC_RELAXED, __HIP_MEMORY_SCOPE_AGENT);

    orow[(size_t)t * U_SZ] = h;                       // fp32 out — off the critical chain
  }
}

// ---- launch ---------------------------------------------------------------
extern "C" void kernel_launch(void* const* d_in, const int* in_sizes, int n_in,
                              void* d_out, int out_size, void* d_ws, size_t ws_size,
                              hipStream_t stream) {
  const float* X   = (const float*)d_in[0];
  const float* Wih = (const float*)d_in[1];
  const float* Whh = (const float*)d_in[2];
  const float* bih = (const float*)d_in[3];
  const float* bhh = (const float*)d_in[4];
  float* out = (float*)d_out;
  char*  ws  = (char*)d_ws;

  u16* Xb    = (u16*)(ws + XB_OFF);
  u16* Wc    = (u16*)(ws + WC_OFF);
  u32* flags = (u32*)(ws + FLAG_OFF);
  u16* hbuf  = (u16*)(ws + HBUF_OFF);

  hipLaunchKernelGGL(k_convX, dim3(32768), dim3(256), 0, stream, X, Xb);
  hipLaunchKernelGGL(k_packW, dim3(4096), dim3(256), 0, stream, Wih, Whh, Wc);
  hipLaunchKernelGGL(k_zero,  dim3(513),  dim3(256), 0, stream, (u32*)hbuf, flags);

  void* args[] = {(void*)&Xb, (void*)&Wc, (void*)&bih, (void*)&bhh,
                  (void*)&hbuf, (void*)&flags, (void*)&out};
  hipLaunchCooperativeKernel((void*)lstm_scan, dim3(256), dim3(512), args, 0, stream);
}